// Round 1
// baseline (2050.375 us; speedup 1.0000x reference)
//
#include <hip/hip_runtime.h>
#include <hip/hip_bf16.h>

// Problem: kv_buffer[loc] = concat(cache_k_nope, cache_k_rope)
//   kv_buffer:    [524288, 576] fp32  (d_in[0])
//   loc:          [32768]       int32 (d_in[1])
//   cache_k_nope: [32768, 512]  fp32  (d_in[2])
//   cache_k_rope: [32768, 64]   fp32  (d_in[3])
// Output: full kv_buffer with scattered rows, fp32.

#define BUF_SLOTS 524288
#define N_LOC     32768
#define ROW_F     576           // floats per row
#define ROW_V     144           // float4 per row
#define NOPE_V    128           // float4 per row of nope
#define ROPE_V    16            // float4 per row of rope

// Scatter rows into out. First N_LOC*NOPE_V threads handle nope elements,
// next N_LOC*ROPE_V threads handle rope. Boundary (4,194,304) is a multiple
// of 256, so every block is homogeneous (no divergence).
__global__ __launch_bounds__(256) void scatter_rows(
    const int* __restrict__ loc,
    const float4* __restrict__ nope,
    const float4* __restrict__ rope,
    float4* __restrict__ out)
{
    const int tid = blockIdx.x * blockDim.x + threadIdx.x;
    const int n_nope = N_LOC * NOPE_V;   // 4,194,304
    if (tid < n_nope) {
        const int token = tid >> 7;          // / NOPE_V
        const int j     = tid & (NOPE_V - 1);
        const int row   = loc[token];
        out[(size_t)row * ROW_V + j] = nope[(size_t)token * NOPE_V + j];
    } else {
        const int t2    = tid - n_nope;
        const int token = t2 >> 4;           // / ROPE_V
        const int j     = t2 & (ROPE_V - 1);
        const int row   = loc[token];
        out[(size_t)row * ROW_V + NOPE_V + j] = rope[(size_t)token * ROPE_V + j];
    }
}

extern "C" void kernel_launch(void* const* d_in, const int* in_sizes, int n_in,
                              void* d_out, int out_size, void* d_ws, size_t ws_size,
                              hipStream_t stream)
{
    const float*  kv_buffer = (const float*)d_in[0];
    const int*    loc       = (const int*)d_in[1];
    const float4* nope      = (const float4*)d_in[2];
    const float4* rope      = (const float4*)d_in[3];
    float*        out       = (float*)d_out;

    // 1) Bulk copy of the pristine buffer into the output (1.208 GB).
    const size_t buf_bytes = (size_t)BUF_SLOTS * ROW_F * sizeof(float);
    hipMemcpyAsync(out, kv_buffer, buf_bytes, hipMemcpyDeviceToDevice, stream);

    // 2) Overwrite the scattered rows (72 MB in, 72 MB out).
    const int total_threads = N_LOC * (NOPE_V + ROPE_V);  // 4,718,592
    const int block = 256;
    const int grid  = total_threads / block;              // 18,432
    scatter_rows<<<grid, block, 0, stream>>>(loc, nope, rope, (float4*)out);
}

// Round 2
// 1839.239 us; speedup vs baseline: 1.1148x; 1.1148x over previous
//
#include <hip/hip_runtime.h>
#include <hip/hip_bf16.h>

// Problem: out = kv_buffer; out[loc] = concat(cache_k_nope, cache_k_rope)
//   kv_buffer:    [524288, 576] fp32  (d_in[0])
//   loc:          [32768]       int32 (d_in[1])  (unique indices)
//   cache_k_nope: [32768, 512]  fp32  (d_in[2])
//   cache_k_rope: [32768, 64]   fp32  (d_in[3])
//
// Strategy: build inverse map mark[row] -> token (or -1) in d_ws, then a
// single fused pass writes every output row exactly once, reading kv_buffer
// only for non-scattered rows. Total HBM traffic ~2.42 GB (vs 2.56 GB for
// copy+scatter, and vs ~4.9 GB measured for the hipMemcpyAsync D2D path,
// which graph capture runs at ~1.5 TB/s effective).

#define BUF_SLOTS 524288
#define N_LOC     32768
#define ROW_V     144           // float4 per row
#define NOPE_V    128           // float4 per row of nope
#define ROPE_V    16            // float4 per row of rope

__global__ __launch_bounds__(256) void init_mark(int* __restrict__ mark)
{
    const int tid = blockIdx.x * 256 + threadIdx.x;
    if (tid < BUF_SLOTS) mark[tid] = -1;
}

__global__ __launch_bounds__(256) void build_mark(const int* __restrict__ loc,
                                                  int* __restrict__ mark)
{
    const int tid = blockIdx.x * 256 + threadIdx.x;
    if (tid < N_LOC) mark[loc[tid]] = tid;
}

// One thread per output float4. t = row*144 + j.
__global__ __launch_bounds__(256) void fused_write(
    const float4* __restrict__ kv,
    const float4* __restrict__ nope,
    const float4* __restrict__ rope,
    const int*    __restrict__ mark,
    float4*       __restrict__ out)
{
    const int t   = blockIdx.x * 256 + threadIdx.x;   // < 75,497,472, fits int
    const int row = t / ROW_V;                        // magic-mul division
    const int j   = t - row * ROW_V;
    const int m   = mark[row];
    float4 v;
    if (m < 0) {
        v = kv[t];
    } else {
        v = (j < NOPE_V) ? nope[m * NOPE_V + j]
                         : rope[m * ROPE_V + (j - NOPE_V)];
    }
    out[t] = v;
}

// Fallback path (ws too small): plain copy + scatter, all our own kernels.
__global__ __launch_bounds__(256) void copy_buf(const float4* __restrict__ src,
                                                float4* __restrict__ dst)
{
    const int t = blockIdx.x * 256 + threadIdx.x;
    dst[t] = src[t];
}

__global__ __launch_bounds__(256) void scatter_rows(
    const int* __restrict__ loc,
    const float4* __restrict__ nope,
    const float4* __restrict__ rope,
    float4* __restrict__ out)
{
    const int tid = blockIdx.x * 256 + threadIdx.x;
    const int n_nope = N_LOC * NOPE_V;   // 4,194,304 (multiple of 256)
    if (tid < n_nope) {
        const int token = tid >> 7;
        const int j     = tid & (NOPE_V - 1);
        const int row   = loc[token];
        out[(size_t)row * ROW_V + j] = nope[(size_t)token * NOPE_V + j];
    } else {
        const int t2    = tid - n_nope;
        const int token = t2 >> 4;
        const int j     = t2 & (ROPE_V - 1);
        const int row   = loc[token];
        out[(size_t)row * ROW_V + NOPE_V + j] = rope[(size_t)token * ROPE_V + j];
    }
}

extern "C" void kernel_launch(void* const* d_in, const int* in_sizes, int n_in,
                              void* d_out, int out_size, void* d_ws, size_t ws_size,
                              hipStream_t stream)
{
    const float4* kv   = (const float4*)d_in[0];
    const int*    loc  = (const int*)d_in[1];
    const float4* nope = (const float4*)d_in[2];
    const float4* rope = (const float4*)d_in[3];
    float4*       out  = (float4*)d_out;

    if (ws_size >= (size_t)BUF_SLOTS * sizeof(int)) {
        int* mark = (int*)d_ws;
        init_mark<<<BUF_SLOTS / 256, 256, 0, stream>>>(mark);
        build_mark<<<N_LOC / 256, 256, 0, stream>>>(loc, mark);
        const int total = BUF_SLOTS * ROW_V;              // 75,497,472
        fused_write<<<total / 256, 256, 0, stream>>>(kv, nope, rope, mark, out);
    } else {
        const int total = BUF_SLOTS * ROW_V;
        copy_buf<<<total / 256, 256, 0, stream>>>(kv, out);
        const int sthreads = N_LOC * (NOPE_V + ROPE_V);   // 4,718,592
        scatter_rows<<<sthreads / 256, 256, 0, stream>>>(loc, nope, rope, out);
    }
}